// Round 12
// baseline (40.149 us; speedup 1.0000x reference)
//
#include <hip/hip_runtime.h>

typedef __attribute__((ext_vector_type(8)))  __bf16 bf16x8;
typedef __attribute__((ext_vector_type(16))) float  f32x16;

#define D_IN  128
#define N_OUT 32
#define K129  129
#define WROW  16512          // 128*129 floats per W row
#define NT    8              // m-tiles (32 rows) per block = 256-row run

// slot -> i permutation within each 32-row block: makes each lane's acc rows
// line up with the 8-elem col chunks its own B-fragments hold. (verified r5-r11)
__device__ __forceinline__ int permSlot(int s) {
    int q = s >> 3, h = (s >> 2) & 1, j = s & 3;
    return 16 * (q >> 1) + 8 * h + 4 * (q & 1) + j;
}

// ---- T14 split staging: issue loads early, convert+ds_write late ----
// LDS tile: [32 rows][16 chunks of 16B], chunk-XOR swizzled (phys c = logical c ^ (r&15)).
// Thread covers phys chunks {wave*128+lane, +64}; loads the logical chunk that
// belongs at that phys slot (same mapping as the verified quad4/5 staging).
#define LOADR(T)                                                                   \
  do {                                                                             \
    const float* s0 = x + (rbase + (long)(T) * 32 + r0s) * D_IN + c0s * 8;         \
    const float* s1 = x + (rbase + (long)(T) * 32 + r1s) * D_IN + c1s * 8;         \
    g0a = *(const float4*)s0; g0b = *(const float4*)(s0 + 4);                      \
    g1a = *(const float4*)s1; g1b = *(const float4*)(s1 + 4);                      \
  } while (0)

#define WRITES(BUF)                                                                \
  do {                                                                             \
    bf16x8 v0 = { (__bf16)g0a.x,(__bf16)g0a.y,(__bf16)g0a.z,(__bf16)g0a.w,         \
                  (__bf16)g0b.x,(__bf16)g0b.y,(__bf16)g0b.z,(__bf16)g0b.w };       \
    bf16x8 v1 = { (__bf16)g1a.x,(__bf16)g1a.y,(__bf16)g1a.z,(__bf16)g1a.w,         \
                  (__bf16)g1b.x,(__bf16)g1b.y,(__bf16)g1b.z,(__bf16)g1b.w };       \
    *(bf16x8*)&tile[BUF][(size_t)p0 * 8] = v0;                                     \
    *(bf16x8*)&tile[BUF][(size_t)p1 * 8] = v1;                                     \
  } while (0)

// lgkm-only barrier: ds_writes must be visible (lgkmcnt), but in-flight
// REGISTER global loads (vmcnt) are private and stay outstanding across it.
// (__syncthreads would drain vmcnt(0) — the m97-ceiling stall.)
#define BARRIER()                                                                  \
  do {                                                                             \
    asm volatile("s_waitcnt lgkmcnt(0)" ::: "memory");                             \
    __builtin_amdgcn_s_barrier();                                                  \
  } while (0)

// One m-tile: 8 swizzled ds_read_b128 -> 4 blocks x 9 MFMA; epilogue dot uses
// the SAME B-frag registers (permuted W lines indices up). Store per tile.
// (quad5's verified COMPUTE, verbatim)
#define COMPUTE(BUF, MT)                                                           \
  {                                                                                \
    const char* tb = (const char*)&tile[BUF][0];                                   \
    bf16x8 Bf[8];                                                                  \
    _Pragma("unroll")                                                              \
    for (int ks = 0; ks < 8; ++ks)                                                 \
      Bf[ks] = *reinterpret_cast<const bf16x8*>(tb + laneB[ks]);                   \
    float s = 0.f;                                                                 \
    _Pragma("unroll")                                                              \
    for (int ct = 0; ct < 4; ++ct) {                                               \
      f32x16 a;                                                                    \
      _Pragma("unroll")                                                            \
      for (int r = 0; r < 16; ++r) a[r] = 0.f;                                     \
      _Pragma("unroll")                                                            \
      for (int ks = 0; ks < 8; ++ks)                                               \
        a = __builtin_amdgcn_mfma_f32_32x32x16_bf16(A[ct][ks], Bf[ks], a, 0, 0, 0);\
      a = __builtin_amdgcn_mfma_f32_32x32x16_bf16(A[ct][8], B8c, a, 0, 0, 0);      \
      _Pragma("unroll")                                                            \
      for (int q = 0; q < 4; ++q)                                                  \
        _Pragma("unroll")                                                          \
        for (int j = 0; j < 4; ++j)                                                \
          s += a[q * 4 + j] * (float)Bf[2 * ct + (q >> 1)][4 * (q & 1) + j];       \
    }                                                                              \
    s += __shfl_xor(s, 32);                                                        \
    if (hi == 0)                                                                   \
      out[(rbase + (long)(MT) * 32 + b32) * N_OUT + o] = s + bias_o;               \
  }

// iteration T (literal): barrier -> compute T -> write tile T+1 -> issue loads T+2
#define ITERF(T)                                                                   \
  {                                                                                \
    BARRIER();                                                                     \
    COMPUTE((T) & 1, (T));                                                         \
    if ((T) < NT - 1) { WRITES(((T) + 1) & 1); }                                   \
    if ((T) < NT - 2) { LOADR((T) + 2); }                                          \
  }

// Single fused kernel: no prep, no workspace. Block = 4 waves = 4 o's over one
// shared 256-row run; A (quadratic W rows + wlin, permuted) stationary in regs,
// loaded straight from f32 W; x staged f32->bf16 into double-buffered LDS.
__global__ __launch_bounds__(256, 2) void quad12(
    const float* __restrict__ x, const float* __restrict__ W,
    const float* __restrict__ bias, float* __restrict__ out)
{
    __shared__ __align__(16) __bf16 tile[2][32 * 128];   // 2 x 8KB, swizzled

    const int tid  = threadIdx.x;
    const int lane = tid & 63;
    const int wave = tid >> 6;              // 0..3 = o within group
    const int b32  = lane & 31, hi = lane >> 5;

    // grid 512 = 8 XCD x (8 runs x 8 o-groups): same-XCD blocks share x runs
    const int bid = blockIdx.x;
    const int xcd = bid & 7, idx = bid >> 3;
    const int run = xcd * 8 + (idx & 7);    // 0..63
    const int og  = idx >> 3;               // 0..7
    const int o   = og * 4 + wave;
    const long rbase = (long)run * (NT * 32);
    const float bias_o = bias[o];

    // ---- stationary A fragments straight from f32 W (verified PREP=0 path) ----
    // lane -> permuted slot row ct*32 + b32, k = hi*8 + r; ks=8 frag holds wlin.
    bf16x8 A[4][9];
    #pragma unroll
    for (int ct = 0; ct < 4; ++ct) {
        const int i = ct * 32 + permSlot(b32);
        const float* wr = W + (size_t)o * WROW + (size_t)i * K129;
        #pragma unroll
        for (int ks = 0; ks < 8; ++ks) {
            bf16x8 f;
            #pragma unroll
            for (int r = 0; r < 8; ++r) f[r] = (__bf16)wr[ks * 16 + hi * 8 + r];
            A[ct][ks] = f;
        }
        bf16x8 f;
        #pragma unroll
        for (int r = 0; r < 8; ++r) f[r] = (__bf16)0.f;
        if (hi == 0) f[0] = (__bf16)wr[128];             // wlin at k=128
        A[ct][8] = f;
    }

    // constant ks=8 B fragment: x~[b,128]=1, rest 0
    bf16x8 B8c;
    #pragma unroll
    for (int r = 0; r < 8; ++r) B8c[r] = (__bf16)0.f;
    if (hi == 0) B8c[0] = (__bf16)1.0f;

    // staging mapping: thread -> phys chunks {wave*128+lane, +64}
    const int p0 = wave * 128 + lane;
    const int r0s = p0 >> 4, c0s = (p0 & 15) ^ (r0s & 15);
    const int p1 = p0 + 64;
    const int r1s = p1 >> 4, c1s = (p1 & 15) ^ (r1s & 15);

    // swizzled ds_read byte offsets (row = b32, logical chunk 2ks+hi)
    const int rm = b32 & 15;
    int laneB[8];
    #pragma unroll
    for (int ks = 0; ks < 8; ++ks)
        laneB[ks] = b32 * 256 + (((ks * 2 + hi) ^ rm) << 4);

    // T14 staging registers (one set; write consumes, then reload)
    float4 g0a, g0b, g1a, g1b;

    // prologue: tile0 -> LDS buf0; tile1 loads in flight
    LOADR(0);
    WRITES(0);
    LOADR(1);

    ITERF(0); ITERF(1); ITERF(2); ITERF(3);
    ITERF(4); ITERF(5); ITERF(6); ITERF(7);
}

extern "C" void kernel_launch(void* const* d_in, const int* in_sizes, int n_in,
                              void* d_out, int out_size, void* d_ws, size_t ws_size,
                              hipStream_t stream) {
    const float* x    = (const float*)d_in[0];
    const float* W    = (const float*)d_in[1];
    const float* bias = (const float*)d_in[2];
    float* out = (float*)d_out;

    // single launch: 512 blocks = 8 XCD x 8 runs x 8 o-groups
    quad12<<<512, 256, 0, stream>>>(x, W, bias, out);
}

// Round 13
// 33.434 us; speedup vs baseline: 1.2009x; 1.2009x over previous
//
#include <hip/hip_runtime.h>

typedef __attribute__((ext_vector_type(8)))  __bf16 bf16x8;
typedef __attribute__((ext_vector_type(16))) float  f32x16;

#define D_IN  128
#define N_OUT 32
#define K129  129
#define WROW  16512          // 128*129 floats per W row
#define NT    8              // m-tiles (32 rows) per block = 256-row run

// slot -> i permutation within each 32-row block: makes each lane's acc rows
// line up with the 8-elem col chunks its own B-fragments hold. (verified r5-r12)
__device__ __forceinline__ int permSlot(int s) {
    int q = s >> 3, h = (s >> 2) & 1, j = s & 3;
    return 16 * (q >> 1) + 8 * h + 4 * (q & 1) + j;
}

// ---- T14 split staging: issue loads early, convert+ds_write late ----
// LDS tile: [32 rows][16 chunks of 16B], chunk-XOR swizzled (phys c = log c ^ (r&15)).
// Thread covers phys chunks {wave*128+lane, +64} (verified quad4/5 mapping).
#define LOADR(T)                                                                   \
  do {                                                                             \
    const float* s0 = x + (rbase + (long)(T) * 32 + r0s) * D_IN + c0s * 8;         \
    const float* s1 = x + (rbase + (long)(T) * 32 + r1s) * D_IN + c1s * 8;         \
    g0a = *(const float4*)s0; g0b = *(const float4*)(s0 + 4);                      \
    g1a = *(const float4*)s1; g1b = *(const float4*)(s1 + 4);                      \
  } while (0)

#define WRITES(BUF)                                                                \
  do {                                                                             \
    bf16x8 v0 = { (__bf16)g0a.x,(__bf16)g0a.y,(__bf16)g0a.z,(__bf16)g0a.w,         \
                  (__bf16)g0b.x,(__bf16)g0b.y,(__bf16)g0b.z,(__bf16)g0b.w };       \
    bf16x8 v1 = { (__bf16)g1a.x,(__bf16)g1a.y,(__bf16)g1a.z,(__bf16)g1a.w,         \
                  (__bf16)g1b.x,(__bf16)g1b.y,(__bf16)g1b.z,(__bf16)g1b.w };       \
    *(bf16x8*)&tile[BUF][(size_t)p0 * 8] = v0;                                     \
    *(bf16x8*)&tile[BUF][(size_t)p1 * 8] = v1;                                     \
  } while (0)

// lgkm-only barrier: ds_writes must be visible (lgkmcnt), but in-flight
// REGISTER global loads (vmcnt) are private and stay outstanding across it.
#define BARRIER()                                                                  \
  do {                                                                             \
    asm volatile("s_waitcnt lgkmcnt(0)" ::: "memory");                             \
    __builtin_amdgcn_s_barrier();                                                  \
  } while (0)

// One m-tile: 8 swizzled ds_read_b128 -> 2 blocks x 9 MFMA; epilogue dot uses
// the SAME B-frag registers. All Bf indices literal: ctl unrolled, sub via
// wave-uniform branch (rule #20 — proven clean in r8/r10/r11).
#define COMPUTE(BUF, MT)                                                           \
  {                                                                                \
    const char* tb = (const char*)&tile[BUF][0];                                   \
    bf16x8 Bf[8];                                                                  \
    _Pragma("unroll")                                                              \
    for (int ks = 0; ks < 8; ++ks)                                                 \
      Bf[ks] = *reinterpret_cast<const bf16x8*>(tb + laneB[ks]);                   \
    float sq[4] = {0.f, 0.f, 0.f, 0.f};                                            \
    _Pragma("unroll")                                                              \
    for (int ctl = 0; ctl < 2; ++ctl) {                                            \
      f32x16 a;                                                                    \
      _Pragma("unroll")                                                            \
      for (int r = 0; r < 16; ++r) a[r] = 0.f;                                     \
      _Pragma("unroll")                                                            \
      for (int ks = 0; ks < 8; ++ks)                                               \
        a = __builtin_amdgcn_mfma_f32_32x32x16_bf16(A[ctl][ks], Bf[ks], a, 0,0,0); \
      a = __builtin_amdgcn_mfma_f32_32x32x16_bf16(A[ctl][8], B8c, a, 0, 0, 0);     \
      if (sub == 0) {                                                              \
        _Pragma("unroll")                                                          \
        for (int q = 0; q < 4; ++q)                                                \
          _Pragma("unroll")                                                        \
          for (int j = 0; j < 4; ++j)                                              \
            sq[q] += a[q * 4 + j] * (float)Bf[2 * ctl + (q >> 1)][4 * (q & 1) + j];\
      } else {                                                                     \
        _Pragma("unroll")                                                          \
        for (int q = 0; q < 4; ++q)                                                \
          _Pragma("unroll")                                                        \
          for (int j = 0; j < 4; ++j)                                              \
            sq[q] += a[q*4 + j] * (float)Bf[4 + 2*ctl + (q >> 1)][4*(q & 1) + j];  \
      }                                                                            \
    }                                                                              \
    float s = (sq[0] + sq[1]) + (sq[2] + sq[3]);                                   \
    s += __shfl_xor(s, 32);                                                        \
    if (hi == 0) red[o2][sub][MT][b32] = s;                                        \
  }

// iteration T (literal): barrier -> compute T -> write tile T+1 -> issue loads T+2
#define ITERF(T)                                                                   \
  {                                                                                \
    BARRIER();                                                                     \
    COMPUTE((T) & 1, (T));                                                         \
    if ((T) < NT - 1) { WRITES(((T) + 1) & 1); }                                   \
    if ((T) < NT - 2) { LOADR((T) + 2); }                                          \
  }

// Single fused kernel, spill-safe wave layout: block = 4 waves = 2 o x 2 i-half
// over one shared 256-row run. A[2][9] (72 regs) straight from f32 W; x staged
// f32->bf16 into double-buffered LDS via T14 split; lgkm-only barriers.
__global__ __launch_bounds__(256, 2) void quad13(
    const float* __restrict__ x, const float* __restrict__ W,
    const float* __restrict__ bias, float* __restrict__ out)
{
    __shared__ __align__(16) __bf16 tile[2][32 * 128];   // 2 x 8KB, swizzled
    __shared__ float red[2][2][NT][32];                  // [o2][sub][mt][b] 8KB

    const int tid  = threadIdx.x;
    const int lane = tid & 63;
    const int wave = tid >> 6;              // 0..3
    const int o2   = wave >> 1;             // which o of the block's 2
    const int sub  = wave & 1;              // i-half (0: i<64, 1: i>=64)
    const int b32  = lane & 31, hi = lane >> 5;

    // grid 1024 = 8 XCD x (16 o-pairs x 8 runs): same-XCD neighbors share a run
    const int bid = blockIdx.x;
    const int xcd = bid & 7, idx = bid >> 3;
    const int opair = idx & 15;
    const int run = xcd * 8 + (idx >> 4);   // 0..63
    const int o   = opair * 2 + o2;
    const long rbase = (long)run * (NT * 32);
    const float bias_o = bias[o];

    // ---- stationary A fragments straight from f32 W (PREP=0 path, verified) ----
    // lane -> permuted slot row (sub*2+ctl)*32 + b32, k = hi*8 + r; ks=8 = wlin.
    bf16x8 A[2][9];
    #pragma unroll
    for (int ctl = 0; ctl < 2; ++ctl) {
        const int i = (sub * 2 + ctl) * 32 + permSlot(b32);
        const float* wr = W + (size_t)o * WROW + (size_t)i * K129;
        #pragma unroll
        for (int ks = 0; ks < 8; ++ks) {
            bf16x8 f;
            #pragma unroll
            for (int r = 0; r < 8; ++r) f[r] = (__bf16)wr[ks * 16 + hi * 8 + r];
            A[ctl][ks] = f;
        }
        bf16x8 f;
        #pragma unroll
        for (int r = 0; r < 8; ++r) f[r] = (__bf16)0.f;
        if (hi == 0) f[0] = (__bf16)wr[128];             // wlin at k=128
        A[ctl][8] = f;
    }

    // constant ks=8 B fragment: x~[b,128]=1, rest 0
    bf16x8 B8c;
    #pragma unroll
    for (int r = 0; r < 8; ++r) B8c[r] = (__bf16)0.f;
    if (hi == 0) B8c[0] = (__bf16)1.0f;

    // staging mapping: thread -> phys chunks {wave*128+lane, +64}
    const int p0 = wave * 128 + lane;
    const int r0s = p0 >> 4, c0s = (p0 & 15) ^ (r0s & 15);
    const int p1 = p0 + 64;
    const int r1s = p1 >> 4, c1s = (p1 & 15) ^ (r1s & 15);

    // swizzled ds_read byte offsets (row = b32, logical chunk 2ks+hi)
    const int rm = b32 & 15;
    int laneB[8];
    #pragma unroll
    for (int ks = 0; ks < 8; ++ks)
        laneB[ks] = b32 * 256 + (((ks * 2 + hi) ^ rm) << 4);

    // T14 staging registers (one set; WRITES consumes, then LOADR refills)
    float4 g0a, g0b, g1a, g1b;

    // prologue: tile0 -> LDS buf0; tile1 loads in flight
    LOADR(0);
    WRITES(0);
    LOADR(1);

    ITERF(0); ITERF(1); ITERF(2); ITERF(3);
    ITERF(4); ITERF(5); ITERF(6); ITERF(7);

    // ---- one-time cross-sub combine + store ----
    __syncthreads();
    if (sub == 0) {
        #pragma unroll
        for (int m = 0; m < NT / 2; ++m) {
            int mt = m * 2 + hi;
            out[(rbase + (long)mt * 32 + b32) * N_OUT + o] =
                red[o2][0][mt][b32] + red[o2][1][mt][b32] + bias_o;
        }
    }
}

extern "C" void kernel_launch(void* const* d_in, const int* in_sizes, int n_in,
                              void* d_out, int out_size, void* d_ws, size_t ws_size,
                              hipStream_t stream) {
    const float* x    = (const float*)d_in[0];
    const float* W    = (const float*)d_in[1];
    const float* bias = (const float*)d_in[2];
    float* out = (float*)d_out;

    // single launch: 1024 blocks = 8 XCD x 16 o-pairs x 8 runs
    quad13<<<1024, 256, 0, stream>>>(x, W, bias, out);
}